// Round 4
// baseline (207.640 us; speedup 1.0000x reference)
//
#include <hip/hip_runtime.h>

// NCA step collapsed: y = single 8->8 channel 3x3 circular conv with folded
// kernel KT[cp][c][9] = sum_f (w1@w0)[c,cp,f] * filters[f].
// out = clamp(grid + (noise<0.5)*conv(grid,K), 0, 1)
//
// v4: LDS-free. Each wave owns a 64-col x 8-row strip of one batch image and
// computes all 8 output channels. Per output row: 8 input ch x 9 direct
// global loads (L1-hot, 3x re-read absorbed by cache) + 576 FMA.
// No barriers, no staging, no integer divides. Column wrap precomputed.

#define B_ 16
#define C_ 8
#define H_ 512
#define W_ 512
#define HID_ 32
#define F_ 5
#define R_ 8   // rows per wave strip

// ---- prep: fold w1 @ w0 @ filters into KT[cp][c][9] ----
__global__ void nca_prep(const float* __restrict__ filters,  // [5][3][3]
                         const float* __restrict__ w0,       // [32][40]
                         const float* __restrict__ w1,       // [8][32]
                         float* __restrict__ KT)             // [8][8][9]
{
    int idx = blockIdx.x * blockDim.x + threadIdx.x;
    if (idx >= C_ * C_ * 9) return;
    int k  = idx % 9;
    int t  = idx / 9;
    int c  = t % C_;   // output channel
    int cp = t / C_;   // input channel
    float acc = 0.f;
    #pragma unroll
    for (int f = 0; f < F_; ++f) {
        float we = 0.f;
        for (int o = 0; o < HID_; ++o)
            we += w1[c * HID_ + o] * w0[o * (C_ * F_) + cp * F_ + f];
        acc += we * filters[f * 9 + k];
    }
    KT[(cp * C_ + c) * 9 + k] = acc;
}

__global__ __launch_bounds__(256) void nca_main(
    const float* __restrict__ grid,
    const float* __restrict__ noise,
    const float* __restrict__ KT,     // [8][8][9]
    float* __restrict__ out)
{
    const int tid  = threadIdx.x;
    const int lane = tid & 63;
    // one strip per wave; force wave-uniform scalar strip id
    int sid = __builtin_amdgcn_readfirstlane(blockIdx.x * 4 + (tid >> 6));
    const int cs = sid & 7;            // column strip (0..7)
    const int rg = (sid >> 3) & 63;    // row group   (0..63)
    const int b  = sid >> 9;           // batch       (0..15)
    const int w0c = cs << 6;
    const int r0  = rg << 3;

    const int col  = w0c + lane;            // no wrap needed (0..511)
    const int colL = (col - 1) & (W_ - 1);
    const int colR = (col + 1) & (W_ - 1);

    for (int rr = 0; rr < R_; ++rr) {
        const int r  = r0 + rr;
        const int rm = (r - 1) & (H_ - 1);
        const int rp = (r + 1) & (H_ - 1);
        const int rows0 = rm, rows1 = r, rows2 = rp;

        float acc[C_];
        #pragma unroll
        for (int c = 0; c < C_; ++c) acc[c] = 0.f;
        float cen[C_];

        #pragma unroll
        for (int cp = 0; cp < C_; ++cp) {
            const float* __restrict__ kk  = KT + cp * (C_ * 9);
            const float* __restrict__ chp = grid + (((b << 3) + cp) << 18);

            float v[3][3];
            {
                const float* p0 = chp + (rows0 << 9);
                v[0][0] = p0[colL]; v[0][1] = p0[col]; v[0][2] = p0[colR];
                const float* p1 = chp + (rows1 << 9);
                v[1][0] = p1[colL]; v[1][1] = p1[col]; v[1][2] = p1[colR];
                const float* p2 = chp + (rows2 << 9);
                v[2][0] = p2[colL]; v[2][1] = p2[col]; v[2][2] = p2[colR];
            }
            cen[cp] = v[1][1];

            #pragma unroll
            for (int c = 0; c < C_; ++c) {
                const float* __restrict__ kc = kk + c * 9;
                acc[c] += kc[0] * v[0][0];
                acc[c] += kc[1] * v[0][1];
                acc[c] += kc[2] * v[0][2];
                acc[c] += kc[3] * v[1][0];
                acc[c] += kc[4] * v[1][1];
                acc[c] += kc[5] * v[1][2];
                acc[c] += kc[6] * v[2][0];
                acc[c] += kc[7] * v[2][1];
                acc[c] += kc[8] * v[2][2];
            }
        }

        // epilogue: mask, residual, clamp, coalesced store
        #pragma unroll
        for (int c = 0; c < C_; ++c) {
            const int gi = (((b << 3) + c) << 18) + (r << 9) + col;
            const float m = noise[gi];
            float o = (m < 0.5f) ? (cen[c] + acc[c]) : cen[c];
            o = fminf(fmaxf(o, 0.0f), 1.0f);
            out[gi] = o;
        }
    }
}

extern "C" void kernel_launch(void* const* d_in, const int* in_sizes, int n_in,
                              void* d_out, int out_size, void* d_ws, size_t ws_size,
                              hipStream_t stream)
{
    const float* grid    = (const float*)d_in[0];
    const float* noise   = (const float*)d_in[1];
    const float* filters = (const float*)d_in[2];
    const float* w0      = (const float*)d_in[3];
    const float* w1      = (const float*)d_in[4];
    float* out = (float*)d_out;
    float* KT  = (float*)d_ws;   // 576 floats

    nca_prep<<<1, 576, 0, stream>>>(filters, w0, w1, KT);

    // strips: 16 batches x 64 row-groups x 8 col-strips = 8192 waves
    // 4 waves per 256-thread block -> 2048 blocks
    nca_main<<<2048, 256, 0, stream>>>(grid, noise, KT, out);
}

// Round 7
// 114.008 us; speedup vs baseline: 1.8213x; 1.8213x over previous
//
#include <hip/hip_runtime.h>

// NCA step collapsed: y = (w1*w0) applied to depthwise-perception == single
// 8->8 channel 3x3 circular conv with folded kernel K[c][c'][3][3].
// out = clamp(grid + (noise<0.5) * conv(grid, K), 0, 1)
//
// v7 == v1 (round-1 kernel, passed at 112.7 us) reverted byte-identical.
// Re-anchoring after two consecutive zero-output failures (v5, v6) whose
// signature matches a never-launched kernel, to distinguish environment
// failure from code failure.

#define B_ 16
#define C_ 8
#define H_ 512
#define W_ 512
#define HID_ 32
#define F_ 5

#define TH 16
#define TW 64

// ---- prep: fold w1 @ w0 @ filters into K[8][8][9] ----
__global__ void nca_prep(const float* __restrict__ filters,  // [5][3][3]
                         const float* __restrict__ w0,       // [32][40]
                         const float* __restrict__ w1,       // [8][32]
                         float* __restrict__ K)               // [8][8][9]
{
    int idx = blockIdx.x * blockDim.x + threadIdx.x;
    if (idx >= C_ * C_ * 9) return;
    int k  = idx % 9;
    int t  = idx / 9;
    int cp = t % C_;   // input channel
    int c  = t / C_;   // output channel
    float acc = 0.f;
    #pragma unroll
    for (int f = 0; f < F_; ++f) {
        float we = 0.f;
        for (int o = 0; o < HID_; ++o)
            we += w1[c * HID_ + o] * w0[o * (C_ * F_) + cp * F_ + f];
        acc += we * filters[f * 9 + k];
    }
    K[idx] = acc;
}

// ---- main: tiled fused conv + mask + residual + clamp ----
__global__ __launch_bounds__(256) void nca_main(
    const float* __restrict__ grid,
    const float* __restrict__ noise,
    const float* __restrict__ K,      // [8][8][9]
    float* __restrict__ out)
{
    __shared__ float lds[C_][TH + 2][TW + 2];   // 8*18*66*4 = 38016 B

    const int b  = blockIdx.z;
    const int h0 = blockIdx.y * TH;
    const int w0 = blockIdx.x * TW;
    const int tid = threadIdx.x;

    // stage 8 channels with 1-px circular halo
    const int PER_CH = (TH + 2) * (TW + 2);       // 1188
    const int TOTAL  = C_ * PER_CH;               // 9504
    for (int i = tid; i < TOTAL; i += 256) {
        int c   = i / PER_CH;
        int rem = i - c * PER_CH;
        int r   = rem / (TW + 2);
        int col = rem - r * (TW + 2);
        int gh  = (h0 + r - 1) & (H_ - 1);
        int gw  = (w0 + col - 1) & (W_ - 1);
        (&lds[0][0][0])[i] = grid[(((b << 3) + c) << 18) + (gh << 9) + gw];
    }
    __syncthreads();

    const int lw  = tid & 63;          // 0..63 -> column in tile
    const int lh0 = (tid >> 6) << 2;   // 0,4,8,12 -> base row of 4-row strip

    float acc[C_][4];
    #pragma unroll
    for (int c = 0; c < C_; ++c)
        #pragma unroll
        for (int p = 0; p < 4; ++p) acc[c][p] = 0.f;

    for (int cp = 0; cp < C_; ++cp) {
        float v[6][3];
        #pragma unroll
        for (int r = 0; r < 6; ++r)
            #pragma unroll
            for (int cc = 0; cc < 3; ++cc)
                v[r][cc] = lds[cp][lh0 + r][lw + cc];

        #pragma unroll
        for (int c = 0; c < C_; ++c) {
            #pragma unroll
            for (int kh = 0; kh < 3; ++kh) {
                #pragma unroll
                for (int kw = 0; kw < 3; ++kw) {
                    const float kv = K[(c * C_ + cp) * 9 + kh * 3 + kw];
                    #pragma unroll
                    for (int p = 0; p < 4; ++p)
                        acc[c][p] += kv * v[p + kh][kw];
                }
            }
        }
    }

    // epilogue: mask, residual, clamp, store
    #pragma unroll
    for (int c = 0; c < C_; ++c) {
        #pragma unroll
        for (int p = 0; p < 4; ++p) {
            const int h  = h0 + lh0 + p;
            const int gi = (((b << 3) + c) << 18) + (h << 9) + (w0 + lw);
            const float g = lds[c][lh0 + p + 1][lw + 1];
            const float m = (noise[gi] < 0.5f) ? 1.0f : 0.0f;
            float nv = g + acc[c][p] * m;
            nv = fminf(fmaxf(nv, 0.0f), 1.0f);
            out[gi] = nv;
        }
    }
}

extern "C" void kernel_launch(void* const* d_in, const int* in_sizes, int n_in,
                              void* d_out, int out_size, void* d_ws, size_t ws_size,
                              hipStream_t stream)
{
    const float* grid    = (const float*)d_in[0];
    const float* noise   = (const float*)d_in[1];
    const float* filters = (const float*)d_in[2];
    const float* w0      = (const float*)d_in[3];
    const float* w1      = (const float*)d_in[4];
    float* out = (float*)d_out;
    float* K   = (float*)d_ws;   // 576 floats

    nca_prep<<<1, 576, 0, stream>>>(filters, w0, w1, K);

    dim3 g(W_ / TW, H_ / TH, B_);
    nca_main<<<g, 256, 0, stream>>>(grid, noise, K, out);
}